// Round 3
// baseline (2036.659 us; speedup 1.0000x reference)
//
#include <hip/hip_runtime.h>
#include <hip/hip_bf16.h>

// GCN 3-layer: gcn_norm -> (GEMM -> gather/segment-sum -> +b -> ELU) x3
// N=100000 nodes, E=3200000 edges, dims 128->32->64->128.
// CSR built once by target (counting sort), atomic-free gather aggregation.
// Inputs: fp32 floats (probed, bf16 fallback), edge_index i32/i64 (probed).
// Output: fp32 (reference output dtype).

constexpr int N = 100000;
constexpr int E = 3200000;

constexpr int CHUNK = 1024;                 // scan chunk per block
constexpr int NB = (N + CHUNK - 1) / CHUNK; // 98 blocks

// adaptive float load: isbf ? bf16 : fp32
__device__ __forceinline__ float ldf(const void* p, int isbf, size_t i) {
    return isbf ? __bfloat162float(((const __hip_bfloat16*)p)[i])
                : ((const float*)p)[i];
}

__device__ __forceinline__ int ld_idx(const void* ei, int is64, size_t pos) {
    return is64 ? (int)((const long long*)ei)[pos] : ((const int*)ei)[pos];
}

// flags[0] = is64 (edge_index), flags[1] = isbf (float tensors)
__global__ void k_probe(const void* ei, const void* x, int* flags) {
    if (threadIdx.x != 0 || blockIdx.x != 0) return;
    // edge index width: int64 data has all values in [0,N); int32 data read
    // as int64 merges adjacent pairs -> huge values at the first probe.
    const long long* p = (const long long*)ei;
    int is64 = 1;
    for (int i = 0; i < 256; i++) {
        long long v = p[i];
        if (v < 0 || v >= (long long)N) { is64 = 0; break; }
    }
    flags[0] = is64;
    // float width: genuine bf16 N(0,1) never has |v| >= 64; fp32 data misread
    // as bf16 has ~24% of u16 halves with exponent >= 133.
    const unsigned short* u = (const unsigned short*)x;
    int big = 0;
    for (int i = 0; i < 4096; i++) {
        int e = (u[i] >> 7) & 0xFF;
        if (e >= 133) big++;  // |v| >= 2^6
    }
    flags[1] = (big < 40) ? 1 : 0;
}

__global__ void k_init(float* deg, int* counts) {
    int i = blockIdx.x * blockDim.x + threadIdx.x;
    if (i < N) { deg[i] = 1.0f; counts[i] = 0; }  // self-loop weight 1 pre-added
}

__global__ void k_deg_count(const void* ei, const int* flags, const void* ew,
                            float* deg, int* counts) {
    int e = blockIdx.x * blockDim.x + threadIdx.x;
    if (e >= E) return;
    int is64 = flags[0], isbf = flags[1];
    int c = ld_idx(ei, is64, (size_t)E + e);
    atomicAdd(&deg[c], ldf(ew, isbf, e));
    atomicAdd(&counts[c], 1);
}

__global__ void k_dinv(float* deg) {
    int i = blockIdx.x * blockDim.x + threadIdx.x;
    if (i < N) deg[i] = rsqrtf(deg[i]);  // deg >= 1 always (self-loop)
}

// --- 3-kernel exclusive scan of counts[N] -> offsets/cursor
__global__ void k_scan_partial(const int* counts, int* blocksum) {
    __shared__ int s[256];
    int b = blockIdx.x, t = threadIdx.x;
    int base = b * CHUNK + t * 4;
    int sum = 0;
#pragma unroll
    for (int j = 0; j < 4; j++) { int idx = base + j; if (idx < N) sum += counts[idx]; }
    s[t] = sum; __syncthreads();
    for (int st = 128; st > 0; st >>= 1) { if (t < st) s[t] += s[t + st]; __syncthreads(); }
    if (t == 0) blocksum[b] = s[0];
}

__global__ void k_scan_top(int* blocksum) {
    __shared__ int s[256];
    int t = threadIdx.x;
    int v = (t < NB) ? blocksum[t] : 0;
    s[t] = v; __syncthreads();
    for (int st = 1; st < 256; st <<= 1) {
        int add = (t >= st) ? s[t - st] : 0;
        __syncthreads();
        s[t] += add;
        __syncthreads();
    }
    if (t < NB) blocksum[t] = s[t] - v;  // exclusive
}

__global__ void k_scan_apply(const int* counts, const int* blocksum, int* offsets, int* cursor) {
    __shared__ int s[256];
    int b = blockIdx.x, t = threadIdx.x;
    int base = b * CHUNK + t * 4;
    int v[4]; int sum = 0;
#pragma unroll
    for (int j = 0; j < 4; j++) { int idx = base + j; v[j] = (idx < N) ? counts[idx] : 0; sum += v[j]; }
    s[t] = sum; __syncthreads();
    for (int st = 1; st < 256; st <<= 1) {
        int add = (t >= st) ? s[t - st] : 0;
        __syncthreads();
        s[t] += add;
        __syncthreads();
    }
    int excl = s[t] - sum + blocksum[b];
#pragma unroll
    for (int j = 0; j < 4; j++) {
        int idx = base + j;
        if (idx < N) { offsets[idx] = excl; cursor[idx] = excl; excl += v[j]; }
    }
}

__global__ void k_fill(const void* ei, const int* flags, const void* ew,
                       const float* dinv, int* cursor, int* src_s, float* nrm_s) {
    int e = blockIdx.x * blockDim.x + threadIdx.x;
    if (e >= E) return;
    int is64 = flags[0], isbf = flags[1];
    int r = ld_idx(ei, is64, e);
    int c = ld_idx(ei, is64, (size_t)E + e);
    float nr = dinv[r] * ldf(ew, isbf, e) * dinv[c];
    int pos = atomicAdd(&cursor[c], 1);
    src_s[pos] = r;
    nrm_s[pos] = nr;
}

// --- small GEMM: H[N,FOUT] = X[N,FIN] @ W[FIN,FOUT], W staged in LDS.
// ADAPT: X is probed dtype (first layer); else X is fp32 workspace.
template <int FIN, int FOUT, bool ADAPT>
__global__ __launch_bounds__(256) void k_gemm(const void* __restrict__ X,
                                              const void* __restrict__ W,
                                              const int* __restrict__ flags,
                                              float* __restrict__ H) {
    constexpr int ROWS = 256 / FOUT;
    __shared__ float wl[FIN * FOUT];
    __shared__ float xl[ROWS][FIN];
    int t = threadIdx.x;
    int isbf = flags[1];
    for (int i = t; i < FIN * FOUT; i += 256) wl[i] = ldf(W, isbf, i);
    int base_row = blockIdx.x * ROWS;
    for (int i = t; i < ROWS * FIN; i += 256) {
        int rr = i / FIN, kk = i % FIN;
        int node = base_row + rr;
        float v = 0.0f;
        if (node < N) {
            size_t idx = (size_t)node * FIN + kk;
            v = ADAPT ? ldf(X, isbf, idx) : ((const float*)X)[idx];
        }
        xl[rr][kk] = v;
    }
    __syncthreads();
    int f = t % FOUT, r = t / FOUT;
    int node = base_row + r;
    if (node >= N) return;
    float acc = 0.0f;
#pragma unroll
    for (int k = 0; k < FIN; k++) acc += xl[r][k] * wl[k * FOUT + f];
    H[(size_t)node * FOUT + f] = acc;
}

// --- aggregation: out[n][f] = sum_edges h[src]*nrm + h[n]*dinv^2 + b[f]; opt ELU
template <int F, bool DOELU>
__global__ __launch_bounds__(256) void k_agg(const float* __restrict__ H,
                                             const int* __restrict__ offsets,
                                             const int* __restrict__ counts,
                                             const int* __restrict__ src_s,
                                             const float* __restrict__ nrm_s,
                                             const float* __restrict__ dinv,
                                             const void* __restrict__ bias,
                                             const int* __restrict__ flags,
                                             float* __restrict__ out) {
    constexpr int NPB = 256 / F;
    int t = threadIdx.x;
    int f = t % F;
    int g = t / F;
    int node = blockIdx.x * NPB + g;
    if (node >= N) return;
    float di = dinv[node];
    float acc = H[(size_t)node * F + f] * di * di;  // self loop
    int start = offsets[node];
    int cnt = counts[node];
    for (int p = 0; p < cnt; p++) {
        int s = src_s[start + p];
        float w = nrm_s[start + p];
        acc += H[(size_t)s * F + f] * w;
    }
    acc += ldf(bias, flags[1], f);
    if (DOELU) acc = (acc > 0.0f) ? acc : expm1f(acc);
    out[(size_t)node * F + f] = acc;
}

// diagnostic fallback: if ws_size is too small, emit sentinel 123.0
__global__ void k_sentinel(float* out, int n) {
    int i = blockIdx.x * blockDim.x + threadIdx.x;
    if (i < n) out[i] = 123.0f;
}

extern "C" void kernel_launch(void* const* d_in, const int* in_sizes, int n_in,
                              void* d_out, int out_size, void* d_ws, size_t ws_size,
                              hipStream_t stream) {
    const void* x  = d_in[0];
    const void* ei = d_in[1];
    const void* ea = d_in[2];
    const void* W1 = d_in[3];
    const void* b1 = d_in[4];
    const void* W2 = d_in[5];
    const void* b2 = d_in[6];
    const void* W3 = d_in[7];
    const void* b3 = d_in[8];
    float* out = (float*)d_out;

    // workspace layout (256B aligned)
    char* ws = (char*)d_ws;
    size_t off = 0;
    auto alloc = [&](size_t bytes) {
        off = (off + 255) & ~(size_t)255;
        size_t r = off;
        off += bytes;
        return r;
    };
    float* deg     = (float*)(ws + alloc((size_t)N * 4));  // becomes dinv in place
    int*   counts  = (int*)  (ws + alloc((size_t)N * 4));
    int*   offsets = (int*)  (ws + alloc((size_t)N * 4));
    int*   cursor  = (int*)  (ws + alloc((size_t)N * 4));
    int*   bsum    = (int*)  (ws + alloc(256 * 4));
    int*   flags   = (int*)  (ws + alloc(256));
    int*   src_s   = (int*)  (ws + alloc((size_t)E * 4));
    float* nrm_s   = (float*)(ws + alloc((size_t)E * 4));
    float* bufA    = (float*)(ws + alloc((size_t)N * 128 * 4)); // h1/h2/h3
    float* bufB    = (float*)(ws + alloc((size_t)N * 64 * 4));  // a1/a2
    size_t need = off;

    if (ws_size < need) {
        // workspace too small — write sentinel so the failure mode is legible
        hipLaunchKernelGGL(k_sentinel, dim3((N * 128 + 255) / 256), dim3(256), 0, stream,
                           out, N * 128);
        return;
    }

    const int TB = 256;
    const int gN = (N + TB - 1) / TB;
    const int gE = (E + TB - 1) / TB;

    hipLaunchKernelGGL(k_probe, dim3(1), dim3(64), 0, stream, ei, x, flags);
    hipLaunchKernelGGL(k_init, dim3(gN), dim3(TB), 0, stream, deg, counts);
    hipLaunchKernelGGL(k_deg_count, dim3(gE), dim3(TB), 0, stream, ei, flags, ea, deg, counts);
    hipLaunchKernelGGL(k_dinv, dim3(gN), dim3(TB), 0, stream, deg);
    hipLaunchKernelGGL(k_scan_partial, dim3(NB), dim3(256), 0, stream, counts, bsum);
    hipLaunchKernelGGL(k_scan_top, dim3(1), dim3(256), 0, stream, bsum);
    hipLaunchKernelGGL(k_scan_apply, dim3(NB), dim3(256), 0, stream, counts, bsum, offsets, cursor);
    hipLaunchKernelGGL(k_fill, dim3(gE), dim3(TB), 0, stream, ei, flags, ea, deg, cursor, src_s, nrm_s);

    // layer 1: 128 -> 32, ELU   (h1 = bufA, a1 = bufB)
    hipLaunchKernelGGL((k_gemm<128, 32, true>), dim3((N + 7) / 8), dim3(256), 0, stream,
                       x, W1, flags, bufA);
    hipLaunchKernelGGL((k_agg<32, true>), dim3((N + 7) / 8), dim3(256), 0, stream,
                       bufA, offsets, counts, src_s, nrm_s, deg, b1, flags, bufB);
    // layer 2: 32 -> 64, ELU    (h2 = bufA, a2 = bufB)
    hipLaunchKernelGGL((k_gemm<32, 64, false>), dim3((N + 3) / 4), dim3(256), 0, stream,
                       bufB, W2, flags, bufA);
    hipLaunchKernelGGL((k_agg<64, true>), dim3((N + 3) / 4), dim3(256), 0, stream,
                       bufA, offsets, counts, src_s, nrm_s, deg, b2, flags, bufB);
    // layer 3: 64 -> 128, no ELU  (h3 = bufA)
    hipLaunchKernelGGL((k_gemm<64, 128, false>), dim3((N + 1) / 2), dim3(256), 0, stream,
                       bufB, W3, flags, bufA);
    hipLaunchKernelGGL((k_agg<128, false>), dim3((N + 1) / 2), dim3(256), 0, stream,
                       bufA, offsets, counts, src_s, nrm_s, deg, b3, flags, out);
}

// Round 4
// 1270.339 us; speedup vs baseline: 1.6032x; 1.6032x over previous
//
#include <hip/hip_runtime.h>
#include <hip/hip_bf16.h>

// GCN 3-layer: gcn_norm -> (GCNConv, ELU) x2 -> GCNConv
// N=100000, E=3200000, dims 128->32->64->128.
// Key algebraic move: aggregation is linear, so agg(h@W) == agg(h)@W.
// We aggregate in the SMALLER feature dim per layer:
//   L1: t1 = x@W1 (128->32); a1 = ELU(agg(t1) + b1)          [gather F=32]
//   L2: s2 = agg(a1);        h2 = ELU(s2@W2 + b2)            [gather F=32]
//   L3: s3 = agg(h2);        out = s3@W3 + b3                [gather F=64]
// CSR built once by target (counting sort); agg is atomic-free gather with
// float4 vector gathers + 4x unrolled edge loop for memory-level parallelism.
// Inputs: fp32 (probed vs bf16), edge_index i64 (probed vs i32). Output fp32.

constexpr int N = 100000;
constexpr int E = 3200000;

constexpr int CHUNK = 1024;                 // scan chunk per block
constexpr int NB = (N + CHUNK - 1) / CHUNK; // 98 blocks

__device__ __forceinline__ float ldf(const void* p, int isbf, size_t i) {
    return isbf ? __bfloat162float(((const __hip_bfloat16*)p)[i])
                : ((const float*)p)[i];
}

__device__ __forceinline__ int ld_idx(const void* ei, int is64, size_t pos) {
    return is64 ? (int)((const long long*)ei)[pos] : ((const int*)ei)[pos];
}

// flags[0] = is64 (edge_index), flags[1] = isbf (float tensors)
__global__ void k_probe(const void* ei, const void* x, int* flags) {
    __shared__ int bad64, bigcnt;
    int t = threadIdx.x;
    if (t == 0) { bad64 = 0; bigcnt = 0; }
    __syncthreads();
    // int64 edge data: all values in [0,N); int32 misread as i64 -> huge.
    long long v = ((const long long*)ei)[t];
    if (v < 0 || v >= (long long)N) atomicAdd(&bad64, 1);
    // bf16 N(0,1) never has |v| >= 2^6; fp32 misread as bf16 -> ~24% do.
    const unsigned short* u = (const unsigned short*)x;
    int big = 0;
    for (int i = t * 16; i < t * 16 + 16; i++) {
        int e = (u[i] >> 7) & 0xFF;
        if (e >= 133) big++;
    }
    atomicAdd(&bigcnt, big);
    __syncthreads();
    if (t == 0) { flags[0] = (bad64 == 0) ? 1 : 0; flags[1] = (bigcnt < 40) ? 1 : 0; }
}

__global__ void k_init(float* deg, int* counts) {
    int i = blockIdx.x * blockDim.x + threadIdx.x;
    if (i < N) { deg[i] = 1.0f; counts[i] = 0; }  // self-loop weight pre-added
}

__global__ void k_deg_count(const void* ei, const int* flags, const void* ew,
                            float* deg, int* counts) {
    int e = blockIdx.x * blockDim.x + threadIdx.x;
    if (e >= E) return;
    int is64 = flags[0], isbf = flags[1];
    int c = ld_idx(ei, is64, (size_t)E + e);
    atomicAdd(&deg[c], ldf(ew, isbf, e));
    atomicAdd(&counts[c], 1);
}

__global__ void k_dinv(float* deg) {
    int i = blockIdx.x * blockDim.x + threadIdx.x;
    if (i < N) deg[i] = rsqrtf(deg[i]);  // deg >= 1 (self-loop)
}

// --- 3-kernel exclusive scan of counts[N] -> offsets/cursor
__global__ void k_scan_partial(const int* counts, int* blocksum) {
    __shared__ int s[256];
    int b = blockIdx.x, t = threadIdx.x;
    int base = b * CHUNK + t * 4;
    int sum = 0;
#pragma unroll
    for (int j = 0; j < 4; j++) { int idx = base + j; if (idx < N) sum += counts[idx]; }
    s[t] = sum; __syncthreads();
    for (int st = 128; st > 0; st >>= 1) { if (t < st) s[t] += s[t + st]; __syncthreads(); }
    if (t == 0) blocksum[b] = s[0];
}

__global__ void k_scan_top(int* blocksum) {
    __shared__ int s[256];
    int t = threadIdx.x;
    int v = (t < NB) ? blocksum[t] : 0;
    s[t] = v; __syncthreads();
    for (int st = 1; st < 256; st <<= 1) {
        int add = (t >= st) ? s[t - st] : 0;
        __syncthreads();
        s[t] += add;
        __syncthreads();
    }
    if (t < NB) blocksum[t] = s[t] - v;  // exclusive
}

__global__ void k_scan_apply(const int* counts, const int* blocksum, int* offsets, int* cursor) {
    __shared__ int s[256];
    int b = blockIdx.x, t = threadIdx.x;
    int base = b * CHUNK + t * 4;
    int v[4]; int sum = 0;
#pragma unroll
    for (int j = 0; j < 4; j++) { int idx = base + j; v[j] = (idx < N) ? counts[idx] : 0; sum += v[j]; }
    s[t] = sum; __syncthreads();
    for (int st = 1; st < 256; st <<= 1) {
        int add = (t >= st) ? s[t - st] : 0;
        __syncthreads();
        s[t] += add;
        __syncthreads();
    }
    int excl = s[t] - sum + blocksum[b];
#pragma unroll
    for (int j = 0; j < 4; j++) {
        int idx = base + j;
        if (idx < N) { offsets[idx] = excl; cursor[idx] = excl; excl += v[j]; }
    }
}

// fill CSR: epk[pos] = (src, norm-bits) as one 8B store
__global__ void k_fill(const void* ei, const int* flags, const void* ew,
                       const float* dinv, int* cursor, int2* epk) {
    int e = blockIdx.x * blockDim.x + threadIdx.x;
    if (e >= E) return;
    int is64 = flags[0], isbf = flags[1];
    int r = ld_idx(ei, is64, e);
    int c = ld_idx(ei, is64, (size_t)E + e);
    float nr = dinv[r] * ldf(ew, isbf, e) * dinv[c];
    int pos = atomicAdd(&cursor[c], 1);
    epk[pos] = make_int2(r, __float_as_int(nr));
}

// --- small GEMM: H[N,FOUT] = X[N,FIN] @ W[FIN,FOUT], W staged in LDS.
// Optional epilogue: +bias, ELU. ADAPT: X probed dtype (layer-1 input).
template <int FIN, int FOUT, bool ADAPT, bool BIAS, bool ELU>
__global__ __launch_bounds__(256) void k_gemm(const void* __restrict__ X,
                                              const void* __restrict__ W,
                                              const void* __restrict__ bias,
                                              const int* __restrict__ flags,
                                              float* __restrict__ H) {
    constexpr int ROWS = 256 / FOUT;
    __shared__ float wl[FIN * FOUT];
    __shared__ float xl[ROWS][FIN];
    int t = threadIdx.x;
    int isbf = flags[1];
    for (int i = t; i < FIN * FOUT; i += 256) wl[i] = ldf(W, isbf, i);
    int base_row = blockIdx.x * ROWS;
    for (int i = t; i < ROWS * FIN; i += 256) {
        int rr = i / FIN, kk = i % FIN;
        int node = base_row + rr;
        float v = 0.0f;
        if (node < N) {
            size_t idx = (size_t)node * FIN + kk;
            v = ADAPT ? ldf(X, isbf, idx) : ((const float*)X)[idx];
        }
        xl[rr][kk] = v;
    }
    __syncthreads();
    int f = t % FOUT, r = t / FOUT;
    int node = base_row + r;
    if (node >= N) return;
    float acc = 0.0f;
#pragma unroll
    for (int k = 0; k < FIN; k++) acc += xl[r][k] * wl[k * FOUT + f];
    if (BIAS) acc += ldf(bias, isbf, f);
    if (ELU) acc = (acc > 0.0f) ? acc : expm1f(acc);
    H[(size_t)node * FOUT + f] = acc;
}

// --- aggregation (pure linear + optional bias/ELU):
// out[n][:] = sum_e nrm_e * H[src_e][:] + dinv[n]^2 * H[n][:] (+b, ELU)
// float4 per lane, F/4 lanes per node, edge loop unrolled x4 for MLP.
template <int F, bool BIAS, bool ELU>
__global__ __launch_bounds__(256) void k_agg(const float4* __restrict__ H4,
                                             const int* __restrict__ offsets,
                                             const int* __restrict__ counts,
                                             const int2* __restrict__ epk,
                                             const float* __restrict__ dinv,
                                             const void* __restrict__ bias,
                                             const int* __restrict__ flags,
                                             float4* __restrict__ out4) {
    constexpr int LPN = F / 4;        // lanes per node
    constexpr int NPB = 256 / LPN;    // nodes per block
    constexpr int STR = F / 4;        // float4 stride per row
    int t = threadIdx.x;
    int lane = t % LPN;
    int g = t / LPN;
    int node = blockIdx.x * NPB + g;
    if (node >= N) return;
    float di = dinv[node];
    float4 h = H4[(size_t)node * STR + lane];
    float sw = di * di;
    float4 acc;
    acc.x = h.x * sw; acc.y = h.y * sw; acc.z = h.z * sw; acc.w = h.w * sw;
    int p = offsets[node];
    int pend = p + counts[node];
    for (; p + 4 <= pend; p += 4) {
        int2 e0 = epk[p], e1 = epk[p + 1], e2 = epk[p + 2], e3 = epk[p + 3];
        float4 h0 = H4[(size_t)e0.x * STR + lane];
        float4 h1 = H4[(size_t)e1.x * STR + lane];
        float4 h2 = H4[(size_t)e2.x * STR + lane];
        float4 h3 = H4[(size_t)e3.x * STR + lane];
        float w0 = __int_as_float(e0.y), w1 = __int_as_float(e1.y);
        float w2 = __int_as_float(e2.y), w3 = __int_as_float(e3.y);
        acc.x += h0.x * w0 + h1.x * w1 + h2.x * w2 + h3.x * w3;
        acc.y += h0.y * w0 + h1.y * w1 + h2.y * w2 + h3.y * w3;
        acc.z += h0.z * w0 + h1.z * w1 + h2.z * w2 + h3.z * w3;
        acc.w += h0.w * w0 + h1.w * w1 + h2.w * w2 + h3.w * w3;
    }
    for (; p < pend; p++) {
        int2 e = epk[p];
        float4 hh = H4[(size_t)e.x * STR + lane];
        float w = __int_as_float(e.y);
        acc.x += hh.x * w; acc.y += hh.y * w; acc.z += hh.z * w; acc.w += hh.w * w;
    }
    if (BIAS) {
        int fb = lane * 4;
        int isbf = flags[1];
        acc.x += ldf(bias, isbf, fb);
        acc.y += ldf(bias, isbf, fb + 1);
        acc.z += ldf(bias, isbf, fb + 2);
        acc.w += ldf(bias, isbf, fb + 3);
    }
    if (ELU) {
        acc.x = (acc.x > 0.0f) ? acc.x : expm1f(acc.x);
        acc.y = (acc.y > 0.0f) ? acc.y : expm1f(acc.y);
        acc.z = (acc.z > 0.0f) ? acc.z : expm1f(acc.z);
        acc.w = (acc.w > 0.0f) ? acc.w : expm1f(acc.w);
    }
    out4[(size_t)node * STR + lane] = acc;
}

// diagnostic fallback: if ws_size too small, emit sentinel 123.0
__global__ void k_sentinel(float* out, int n) {
    int i = blockIdx.x * blockDim.x + threadIdx.x;
    if (i < n) out[i] = 123.0f;
}

extern "C" void kernel_launch(void* const* d_in, const int* in_sizes, int n_in,
                              void* d_out, int out_size, void* d_ws, size_t ws_size,
                              hipStream_t stream) {
    const void* x  = d_in[0];
    const void* ei = d_in[1];
    const void* ea = d_in[2];
    const void* W1 = d_in[3];
    const void* b1 = d_in[4];
    const void* W2 = d_in[5];
    const void* b2 = d_in[6];
    const void* W3 = d_in[7];
    const void* b3 = d_in[8];
    float* out = (float*)d_out;

    // workspace layout (256B aligned)
    char* ws = (char*)d_ws;
    size_t off = 0;
    auto alloc = [&](size_t bytes) {
        off = (off + 255) & ~(size_t)255;
        size_t r = off;
        off += bytes;
        return r;
    };
    float* deg     = (float*)(ws + alloc((size_t)N * 4));  // becomes dinv in place
    int*   counts  = (int*)  (ws + alloc((size_t)N * 4));
    int*   offsets = (int*)  (ws + alloc((size_t)N * 4));
    int*   cursor  = (int*)  (ws + alloc((size_t)N * 4));
    int*   bsum    = (int*)  (ws + alloc(256 * 4));
    int*   flags   = (int*)  (ws + alloc(256));
    int2*  epk     = (int2*) (ws + alloc((size_t)E * 8));
    float* bufA    = (float*)(ws + alloc((size_t)N * 64 * 4));
    float* bufB    = (float*)(ws + alloc((size_t)N * 64 * 4));
    size_t need = off;

    if (ws_size < need) {
        hipLaunchKernelGGL(k_sentinel, dim3((N * 128 + 255) / 256), dim3(256), 0, stream,
                           out, N * 128);
        return;
    }

    const int TB = 256;
    const int gN = (N + TB - 1) / TB;
    const int gE = (E + TB - 1) / TB;

    hipLaunchKernelGGL(k_probe, dim3(1), dim3(256), 0, stream, ei, x, flags);
    hipLaunchKernelGGL(k_init, dim3(gN), dim3(TB), 0, stream, deg, counts);
    hipLaunchKernelGGL(k_deg_count, dim3(gE), dim3(TB), 0, stream, ei, flags, ea, deg, counts);
    hipLaunchKernelGGL(k_dinv, dim3(gN), dim3(TB), 0, stream, deg);
    hipLaunchKernelGGL(k_scan_partial, dim3(NB), dim3(256), 0, stream, counts, bsum);
    hipLaunchKernelGGL(k_scan_top, dim3(1), dim3(256), 0, stream, bsum);
    hipLaunchKernelGGL(k_scan_apply, dim3(NB), dim3(256), 0, stream, counts, bsum, offsets, cursor);
    hipLaunchKernelGGL(k_fill, dim3(gE), dim3(TB), 0, stream, ei, flags, ea, deg, cursor, epk);

    // L1: t1 = x@W1 (bufA, F=32); a1 = ELU(agg(t1)+b1) (bufB)
    hipLaunchKernelGGL((k_gemm<128, 32, true, false, false>), dim3((N + 7) / 8), dim3(256), 0, stream,
                       x, W1, nullptr, flags, bufA);
    hipLaunchKernelGGL((k_agg<32, true, true>), dim3((N + 31) / 32), dim3(256), 0, stream,
                       (const float4*)bufA, offsets, counts, epk, deg, b1, flags, (float4*)bufB);
    // L2: s2 = agg(a1) (bufA, F=32); h2 = ELU(s2@W2+b2) (bufB, F=64)
    hipLaunchKernelGGL((k_agg<32, false, false>), dim3((N + 31) / 32), dim3(256), 0, stream,
                       (const float4*)bufB, offsets, counts, epk, deg, nullptr, flags, (float4*)bufA);
    hipLaunchKernelGGL((k_gemm<32, 64, false, true, true>), dim3((N + 3) / 4), dim3(256), 0, stream,
                       bufA, W2, b2, flags, bufB);
    // L3: s3 = agg(h2) (bufA, F=64); out = s3@W3+b3 (d_out, F=128)
    hipLaunchKernelGGL((k_agg<64, false, false>), dim3((N + 15) / 16), dim3(256), 0, stream,
                       (const float4*)bufB, offsets, counts, epk, deg, nullptr, flags, (float4*)bufA);
    hipLaunchKernelGGL((k_gemm<64, 128, false, true, false>), dim3((N + 1) / 2), dim3(256), 0, stream,
                       bufA, W3, b3, flags, out);
}

// Round 5
// 902.942 us; speedup vs baseline: 2.2556x; 1.4069x over previous
//
#include <hip/hip_runtime.h>
#include <hip/hip_bf16.h>

// GCN 3-layer: gcn_norm -> (GCNConv, ELU) x2 -> GCNConv
// N=100000, E=3200000, dims 128->32->64->128.
// agg is linear => aggregate in the SMALLER feature dim per layer:
//   L1: t1 = x@W1 (128->32); a1 = ELU(agg(t1) + b1)          [gather F=32]
//   L2: s2 = agg(a1);        h2 = ELU(s2@W2 + b2)            [gather F=32]
//   L3: s3 = agg(h2);        out = s3@W3 + b3                [gather F=64]
// CSR built once by target (counting sort); agg = atomic-free float4 gather,
// 4x unrolled for MLP. GEMMs: register-blocked 64-row tiles, X staged
// transposed in LDS (b64/b128 inner reads), W staged once per 64 rows.
// Inputs: fp32 (probed vs bf16), edge_index i64 (probed vs i32). Output fp32.

constexpr int N = 100000;
constexpr int E = 3200000;

constexpr int CHUNK = 1024;                 // scan chunk per block
constexpr int NB = (N + CHUNK - 1) / CHUNK; // 98 blocks

__device__ __forceinline__ float ldf(const void* p, int isbf, size_t i) {
    return isbf ? __bfloat162float(((const __hip_bfloat16*)p)[i])
                : ((const float*)p)[i];
}

__device__ __forceinline__ int ld_idx(const void* ei, int is64, size_t pos) {
    return is64 ? (int)((const long long*)ei)[pos] : ((const int*)ei)[pos];
}

// flags[0] = is64 (edge_index), flags[1] = isbf (float tensors)
__global__ void k_probe(const void* ei, const void* x, int* flags) {
    __shared__ int bad64, bigcnt;
    int t = threadIdx.x;
    if (t == 0) { bad64 = 0; bigcnt = 0; }
    __syncthreads();
    long long v = ((const long long*)ei)[t];
    if (v < 0 || v >= (long long)N) atomicAdd(&bad64, 1);
    const unsigned short* u = (const unsigned short*)x;
    int big = 0;
    for (int i = t * 16; i < t * 16 + 16; i++) {
        int e = (u[i] >> 7) & 0xFF;
        if (e >= 133) big++;
    }
    atomicAdd(&bigcnt, big);
    __syncthreads();
    if (t == 0) { flags[0] = (bad64 == 0) ? 1 : 0; flags[1] = (bigcnt < 40) ? 1 : 0; }
}

__global__ void k_init(float* deg, int* counts) {
    int i = blockIdx.x * blockDim.x + threadIdx.x;
    if (i < N) { deg[i] = 1.0f; counts[i] = 0; }  // self-loop weight pre-added
}

__global__ void k_deg_count(const void* ei, const int* flags, const void* ew,
                            float* deg, int* counts) {
    int e = blockIdx.x * blockDim.x + threadIdx.x;
    if (e >= E) return;
    int is64 = flags[0], isbf = flags[1];
    int c = ld_idx(ei, is64, (size_t)E + e);
    atomicAdd(&deg[c], ldf(ew, isbf, e));
    atomicAdd(&counts[c], 1);
}

__global__ void k_dinv(float* deg) {
    int i = blockIdx.x * blockDim.x + threadIdx.x;
    if (i < N) deg[i] = rsqrtf(deg[i]);  // deg >= 1 (self-loop)
}

// --- 3-kernel exclusive scan of counts[N] -> offsets/cursor
__global__ void k_scan_partial(const int* counts, int* blocksum) {
    __shared__ int s[256];
    int b = blockIdx.x, t = threadIdx.x;
    int base = b * CHUNK + t * 4;
    int sum = 0;
#pragma unroll
    for (int j = 0; j < 4; j++) { int idx = base + j; if (idx < N) sum += counts[idx]; }
    s[t] = sum; __syncthreads();
    for (int st = 128; st > 0; st >>= 1) { if (t < st) s[t] += s[t + st]; __syncthreads(); }
    if (t == 0) blocksum[b] = s[0];
}

__global__ void k_scan_top(int* blocksum) {
    __shared__ int s[256];
    int t = threadIdx.x;
    int v = (t < NB) ? blocksum[t] : 0;
    s[t] = v; __syncthreads();
    for (int st = 1; st < 256; st <<= 1) {
        int add = (t >= st) ? s[t - st] : 0;
        __syncthreads();
        s[t] += add;
        __syncthreads();
    }
    if (t < NB) blocksum[t] = s[t] - v;  // exclusive
}

__global__ void k_scan_apply(const int* counts, const int* blocksum, int* offsets, int* cursor) {
    __shared__ int s[256];
    int b = blockIdx.x, t = threadIdx.x;
    int base = b * CHUNK + t * 4;
    int v[4]; int sum = 0;
#pragma unroll
    for (int j = 0; j < 4; j++) { int idx = base + j; v[j] = (idx < N) ? counts[idx] : 0; sum += v[j]; }
    s[t] = sum; __syncthreads();
    for (int st = 1; st < 256; st <<= 1) {
        int add = (t >= st) ? s[t - st] : 0;
        __syncthreads();
        s[t] += add;
        __syncthreads();
    }
    int excl = s[t] - sum + blocksum[b];
#pragma unroll
    for (int j = 0; j < 4; j++) {
        int idx = base + j;
        if (idx < N) { offsets[idx] = excl; cursor[idx] = excl; excl += v[j]; }
    }
}

// fill CSR: epk[pos] = (src, norm-bits) as one 8B store
__global__ void k_fill(const void* ei, const int* flags, const void* ew,
                       const float* dinv, int* cursor, int2* epk) {
    int e = blockIdx.x * blockDim.x + threadIdx.x;
    if (e >= E) return;
    int is64 = flags[0], isbf = flags[1];
    int r = ld_idx(ei, is64, e);
    int c = ld_idx(ei, is64, (size_t)E + e);
    float nr = dinv[r] * ldf(ew, isbf, e) * dinv[c];
    int pos = atomicAdd(&cursor[c], 1);
    epk[pos] = make_int2(r, __float_as_int(nr));
}

// --- register-blocked GEMM: H[N,FOUT] = X[N,FIN] @ W[FIN,FOUT] (+b, ELU)
// 256 threads; TCOLS=FOUT/TN thread-cols x TROWS thread-rows; BR=TROWS*TM
// rows per block. X staged TRANSPOSED (xt[k][row], +1 pad) so the inner
// loop reads a[TM] contiguously; W staged row-major (wl[k][c] contiguous).
template <int FIN, int FOUT, int TM, int TN, bool ADAPT, bool BIAS, bool ELU>
__global__ __launch_bounds__(256) void k_gemm(const void* __restrict__ X,
                                              const void* __restrict__ W,
                                              const void* __restrict__ bias,
                                              const int* __restrict__ flags,
                                              float* __restrict__ H) {
    constexpr int TCOLS = FOUT / TN;
    constexpr int TROWS = 256 / TCOLS;
    constexpr int BR = TROWS * TM;
    __shared__ float wl[FIN * FOUT];
    __shared__ float xt[FIN][BR + 1];
    int t = threadIdx.x;
    int isbf = flags[1];
    int base = blockIdx.x * BR;

    // stage W (contiguous float4 when fp32)
    if (!isbf) {
        const float4* W4 = (const float4*)W;
        float4* wl4 = (float4*)wl;
        for (int i = t; i < FIN * FOUT / 4; i += 256) wl4[i] = W4[i];
    } else {
        for (int i = t; i < FIN * FOUT; i += 256)
            wl[i] = __bfloat162float(((const __hip_bfloat16*)W)[i]);
    }
    // stage X transposed
    if (!ADAPT || !isbf) {
        const float4* X4 = (const float4*)X;
        for (int i = t; i < BR * FIN / 4; i += 256) {
            int row = i / (FIN / 4);
            int kq = i % (FIN / 4);
            int node = base + row;
            float4 v = make_float4(0.f, 0.f, 0.f, 0.f);
            if (node < N) v = X4[(size_t)node * (FIN / 4) + kq];
            int k = kq * 4;
            xt[k][row] = v.x; xt[k + 1][row] = v.y;
            xt[k + 2][row] = v.z; xt[k + 3][row] = v.w;
        }
    } else {
        for (int i = t; i < BR * FIN; i += 256) {
            int row = i / FIN, k = i % FIN;
            int node = base + row;
            float v = (node < N)
                ? __bfloat162float(((const __hip_bfloat16*)X)[(size_t)node * FIN + k]) : 0.f;
            xt[k][row] = v;
        }
    }
    __syncthreads();

    int tcol = t % TCOLS, trow = t / TCOLS;
    int r0 = trow * TM, c0 = tcol * TN;
    float acc[TM][TN] = {};
#pragma unroll 4
    for (int k = 0; k < FIN; k++) {
        float a[TM], b[TN];
#pragma unroll
        for (int m = 0; m < TM; m++) a[m] = xt[k][r0 + m];
#pragma unroll
        for (int n = 0; n < TN; n++) b[n] = wl[k * FOUT + c0 + n];
#pragma unroll
        for (int m = 0; m < TM; m++)
#pragma unroll
            for (int n = 0; n < TN; n++) acc[m][n] += a[m] * b[n];
    }
#pragma unroll
    for (int m = 0; m < TM; m++) {
        int node = base + r0 + m;
        if (node >= N) continue;
#pragma unroll
        for (int n = 0; n < TN; n++) {
            float v = acc[m][n];
            if (BIAS) v += ldf(bias, isbf, c0 + n);
            if (ELU) v = (v > 0.0f) ? v : expm1f(v);
            H[(size_t)node * FOUT + c0 + n] = v;
        }
    }
}

// --- aggregation (linear + optional bias/ELU):
// out[n][:] = sum_e nrm_e * H[src_e][:] + dinv[n]^2 * H[n][:] (+b, ELU)
template <int F, bool BIAS, bool ELU>
__global__ __launch_bounds__(256) void k_agg(const float4* __restrict__ H4,
                                             const int* __restrict__ offsets,
                                             const int* __restrict__ counts,
                                             const int2* __restrict__ epk,
                                             const float* __restrict__ dinv,
                                             const void* __restrict__ bias,
                                             const int* __restrict__ flags,
                                             float4* __restrict__ out4) {
    constexpr int LPN = F / 4;        // lanes per node
    constexpr int NPB = 256 / LPN;    // nodes per block
    constexpr int STR = F / 4;        // float4 stride per row
    int t = threadIdx.x;
    int lane = t % LPN;
    int g = t / LPN;
    int node = blockIdx.x * NPB + g;
    if (node >= N) return;
    float di = dinv[node];
    float4 h = H4[(size_t)node * STR + lane];
    float sw = di * di;
    float4 acc;
    acc.x = h.x * sw; acc.y = h.y * sw; acc.z = h.z * sw; acc.w = h.w * sw;
    int p = offsets[node];
    int pend = p + counts[node];
    for (; p + 4 <= pend; p += 4) {
        int2 e0 = epk[p], e1 = epk[p + 1], e2 = epk[p + 2], e3 = epk[p + 3];
        float4 h0 = H4[(size_t)e0.x * STR + lane];
        float4 h1 = H4[(size_t)e1.x * STR + lane];
        float4 h2 = H4[(size_t)e2.x * STR + lane];
        float4 h3 = H4[(size_t)e3.x * STR + lane];
        float w0 = __int_as_float(e0.y), w1 = __int_as_float(e1.y);
        float w2 = __int_as_float(e2.y), w3 = __int_as_float(e3.y);
        acc.x += h0.x * w0 + h1.x * w1 + h2.x * w2 + h3.x * w3;
        acc.y += h0.y * w0 + h1.y * w1 + h2.y * w2 + h3.y * w3;
        acc.z += h0.z * w0 + h1.z * w1 + h2.z * w2 + h3.z * w3;
        acc.w += h0.w * w0 + h1.w * w1 + h2.w * w2 + h3.w * w3;
    }
    for (; p < pend; p++) {
        int2 e = epk[p];
        float4 hh = H4[(size_t)e.x * STR + lane];
        float w = __int_as_float(e.y);
        acc.x += hh.x * w; acc.y += hh.y * w; acc.z += hh.z * w; acc.w += hh.w * w;
    }
    if (BIAS) {
        int fb = lane * 4;
        int isbf = flags[1];
        acc.x += ldf(bias, isbf, fb);
        acc.y += ldf(bias, isbf, fb + 1);
        acc.z += ldf(bias, isbf, fb + 2);
        acc.w += ldf(bias, isbf, fb + 3);
    }
    if (ELU) {
        acc.x = (acc.x > 0.0f) ? acc.x : expm1f(acc.x);
        acc.y = (acc.y > 0.0f) ? acc.y : expm1f(acc.y);
        acc.z = (acc.z > 0.0f) ? acc.z : expm1f(acc.z);
        acc.w = (acc.w > 0.0f) ? acc.w : expm1f(acc.w);
    }
    out4[(size_t)node * STR + lane] = acc;
}

// diagnostic fallback: if ws_size too small, emit sentinel 123.0
__global__ void k_sentinel(float* out, int n) {
    int i = blockIdx.x * blockDim.x + threadIdx.x;
    if (i < n) out[i] = 123.0f;
}

extern "C" void kernel_launch(void* const* d_in, const int* in_sizes, int n_in,
                              void* d_out, int out_size, void* d_ws, size_t ws_size,
                              hipStream_t stream) {
    const void* x  = d_in[0];
    const void* ei = d_in[1];
    const void* ea = d_in[2];
    const void* W1 = d_in[3];
    const void* b1 = d_in[4];
    const void* W2 = d_in[5];
    const void* b2 = d_in[6];
    const void* W3 = d_in[7];
    const void* b3 = d_in[8];
    float* out = (float*)d_out;

    // workspace layout (256B aligned)
    char* ws = (char*)d_ws;
    size_t off = 0;
    auto alloc = [&](size_t bytes) {
        off = (off + 255) & ~(size_t)255;
        size_t r = off;
        off += bytes;
        return r;
    };
    float* deg     = (float*)(ws + alloc((size_t)N * 4));  // becomes dinv in place
    int*   counts  = (int*)  (ws + alloc((size_t)N * 4));
    int*   offsets = (int*)  (ws + alloc((size_t)N * 4));
    int*   cursor  = (int*)  (ws + alloc((size_t)N * 4));
    int*   bsum    = (int*)  (ws + alloc(256 * 4));
    int*   flags   = (int*)  (ws + alloc(256));
    int2*  epk     = (int2*) (ws + alloc((size_t)E * 8));
    float* bufA    = (float*)(ws + alloc((size_t)N * 64 * 4));
    float* bufB    = (float*)(ws + alloc((size_t)N * 64 * 4));
    size_t need = off;

    if (ws_size < need) {
        hipLaunchKernelGGL(k_sentinel, dim3((N * 128 + 255) / 256), dim3(256), 0, stream,
                           out, N * 128);
        return;
    }

    const int TB = 256;
    const int gN = (N + TB - 1) / TB;
    const int gE = (E + TB - 1) / TB;

    hipLaunchKernelGGL(k_probe, dim3(1), dim3(256), 0, stream, ei, x, flags);
    hipLaunchKernelGGL(k_init, dim3(gN), dim3(TB), 0, stream, deg, counts);
    hipLaunchKernelGGL(k_deg_count, dim3(gE), dim3(TB), 0, stream, ei, flags, ea, deg, counts);
    hipLaunchKernelGGL(k_dinv, dim3(gN), dim3(TB), 0, stream, deg);
    hipLaunchKernelGGL(k_scan_partial, dim3(NB), dim3(256), 0, stream, counts, bsum);
    hipLaunchKernelGGL(k_scan_top, dim3(1), dim3(256), 0, stream, bsum);
    hipLaunchKernelGGL(k_scan_apply, dim3(NB), dim3(256), 0, stream, counts, bsum, offsets, cursor);
    hipLaunchKernelGGL(k_fill, dim3(gE), dim3(TB), 0, stream, ei, flags, ea, deg, cursor, epk);

    // L1: t1 = x@W1 (bufA, F=32); a1 = ELU(agg(t1)+b1) (bufB)
    //   TM=2,TN=4 -> TCOLS=8,TROWS=32,BR=64; LDS = 16K(wl) + 33K(xt)
    hipLaunchKernelGGL((k_gemm<128, 32, 2, 4, true, false, false>),
                       dim3((N + 63) / 64), dim3(256), 0, stream, x, W1, nullptr, flags, bufA);
    hipLaunchKernelGGL((k_agg<32, true, true>), dim3((N + 31) / 32), dim3(256), 0, stream,
                       (const float4*)bufA, offsets, counts, epk, deg, b1, flags, (float4*)bufB);
    // L2: s2 = agg(a1) (bufA, F=32); h2 = ELU(s2@W2+b2) (bufB, F=64)
    //   TM=4,TN=4 -> TCOLS=16,TROWS=16,BR=64; LDS = 8K + 8K
    hipLaunchKernelGGL((k_agg<32, false, false>), dim3((N + 31) / 32), dim3(256), 0, stream,
                       (const float4*)bufB, offsets, counts, epk, deg, nullptr, flags, (float4*)bufA);
    hipLaunchKernelGGL((k_gemm<32, 64, 4, 4, false, true, true>),
                       dim3((N + 63) / 64), dim3(256), 0, stream, bufA, W2, b2, flags, bufB);
    // L3: s3 = agg(h2) (bufA, F=64); out = s3@W3+b3 (d_out, F=128)
    //   TM=4,TN=8 -> TCOLS=16,TROWS=16,BR=64; LDS = 32K + 16K
    hipLaunchKernelGGL((k_agg<64, false, false>), dim3((N + 15) / 16), dim3(256), 0, stream,
                       (const float4*)bufB, offsets, counts, epk, deg, nullptr, flags, (float4*)bufA);
    hipLaunchKernelGGL((k_gemm<64, 128, 4, 8, false, true, false>),
                       dim3((N + 63) / 64), dim3(256), 0, stream, bufA, W3, b3, flags, out);
}

// Round 6
// 769.508 us; speedup vs baseline: 2.6467x; 1.1734x over previous
//
#include <hip/hip_runtime.h>
#include <hip/hip_bf16.h>

// GCN 3-layer: gcn_norm -> (GCNConv, ELU) x2 -> GCNConv
// N=100000, E=3200000, dims 128->32->64->128.
// agg is linear => aggregate in the SMALLER feature dim per layer:
//   L1: t1 = x@W1 (128->32); a1 = ELU(agg(t1) + b1)          [gather F=32]
//   L2: s2 = agg(a1);        h2 = ELU(s2@W2 + b2)            [gather F=32]
//   L3: s3 = agg(h2);        out = s3@W3 + b3                [gather F=64]
// CSR built once by target (counting sort). Histogram pass uses ONE packed
// 64-bit atomic per edge (count<<40 | fixed24(ew)) — device-scope atomics
// write through to memory-side (~32B/atomic observed), so halving atomic
// count halves that traffic. dinv[c] factored out of edge norms (applied
// once per node in agg). GEMMs register-blocked 64-row tiles.
// Inputs: fp32 (probed vs bf16), edge_index i64 (probed vs i32). Output fp32.

constexpr int N = 100000;
constexpr int E = 3200000;

constexpr int CHUNK = 1024;                 // scan chunk per block
constexpr int NB = (N + CHUNK - 1) / CHUNK; // 98 blocks

constexpr float FIX_SCALE = 16777216.0f;    // 2^24
constexpr unsigned long long CNT_ONE = 1ull << 40;
constexpr unsigned long long SUM_MASK = CNT_ONE - 1;

__device__ __forceinline__ float ldf(const void* p, int isbf, size_t i) {
    return isbf ? __bfloat162float(((const __hip_bfloat16*)p)[i])
                : ((const float*)p)[i];
}

__device__ __forceinline__ int ld_idx(const void* ei, int is64, size_t pos) {
    return is64 ? (int)((const long long*)ei)[pos] : ((const int*)ei)[pos];
}

// flags[0] = is64 (edge_index), flags[1] = isbf (float tensors)
__global__ void k_probe(const void* ei, const void* x, int* flags) {
    __shared__ int bad64, bigcnt;
    int t = threadIdx.x;
    if (t == 0) { bad64 = 0; bigcnt = 0; }
    __syncthreads();
    long long v = ((const long long*)ei)[t];
    if (v < 0 || v >= (long long)N) atomicAdd(&bad64, 1);
    const unsigned short* u = (const unsigned short*)x;
    int big = 0;
    for (int i = t * 16; i < t * 16 + 16; i++) {
        int e = (u[i] >> 7) & 0xFF;
        if (e >= 133) big++;
    }
    atomicAdd(&bigcnt, big);
    __syncthreads();
    if (t == 0) { flags[0] = (bad64 == 0) ? 1 : 0; flags[1] = (bigcnt < 40) ? 1 : 0; }
}

__global__ void k_init(unsigned long long* packed) {
    int i = blockIdx.x * blockDim.x + threadIdx.x;
    if (i < N) packed[i] = 0ull;
}

// one packed atomic per edge: count in [40,64), fixed-point ew sum in [0,40)
__global__ void k_deg_count(const void* ei, const int* flags, const void* ew,
                            unsigned long long* packed) {
    int e = blockIdx.x * blockDim.x + threadIdx.x;
    if (e >= E) return;
    int is64 = flags[0], isbf = flags[1];
    int c = ld_idx(ei, is64, (size_t)E + e);
    float w = ldf(ew, isbf, e);
    unsigned long long fx = (unsigned long long)(unsigned int)__float2uint_rn(w * FIX_SCALE);
    atomicAdd(&packed[c], CNT_ONE | fx);
}

// unpack: counts + dinv (deg includes +1 self-loop)
__global__ void k_dinv(const unsigned long long* packed, int* counts, float* dinv) {
    int i = blockIdx.x * blockDim.x + threadIdx.x;
    if (i >= N) return;
    unsigned long long p = packed[i];
    float deg = 1.0f + (float)(p & SUM_MASK) * (1.0f / FIX_SCALE);
    counts[i] = (int)(p >> 40);
    dinv[i] = rsqrtf(deg);
}

// --- 3-kernel exclusive scan of counts[N] -> offsets/cursor
__global__ void k_scan_partial(const int* counts, int* blocksum) {
    __shared__ int s[256];
    int b = blockIdx.x, t = threadIdx.x;
    int base = b * CHUNK + t * 4;
    int sum = 0;
#pragma unroll
    for (int j = 0; j < 4; j++) { int idx = base + j; if (idx < N) sum += counts[idx]; }
    s[t] = sum; __syncthreads();
    for (int st = 128; st > 0; st >>= 1) { if (t < st) s[t] += s[t + st]; __syncthreads(); }
    if (t == 0) blocksum[b] = s[0];
}

__global__ void k_scan_top(int* blocksum) {
    __shared__ int s[256];
    int t = threadIdx.x;
    int v = (t < NB) ? blocksum[t] : 0;
    s[t] = v; __syncthreads();
    for (int st = 1; st < 256; st <<= 1) {
        int add = (t >= st) ? s[t - st] : 0;
        __syncthreads();
        s[t] += add;
        __syncthreads();
    }
    if (t < NB) blocksum[t] = s[t] - v;  // exclusive
}

__global__ void k_scan_apply(const int* counts, const int* blocksum, int* offsets, int* cursor) {
    __shared__ int s[256];
    int b = blockIdx.x, t = threadIdx.x;
    int base = b * CHUNK + t * 4;
    int v[4]; int sum = 0;
#pragma unroll
    for (int j = 0; j < 4; j++) { int idx = base + j; v[j] = (idx < N) ? counts[idx] : 0; sum += v[j]; }
    s[t] = sum; __syncthreads();
    for (int st = 1; st < 256; st <<= 1) {
        int add = (t >= st) ? s[t - st] : 0;
        __syncthreads();
        s[t] += add;
        __syncthreads();
    }
    int excl = s[t] - sum + blocksum[b];
#pragma unroll
    for (int j = 0; j < 4; j++) {
        int idx = base + j;
        if (idx < N) { offsets[idx] = excl; cursor[idx] = excl; excl += v[j]; }
    }
}

// fill CSR: epk[pos] = (src, dinv[src]*ew) — dinv[target] factored out (agg)
__global__ void k_fill(const void* ei, const int* flags, const void* ew,
                       const float* dinv, int* cursor, int2* epk) {
    int e = blockIdx.x * blockDim.x + threadIdx.x;
    if (e >= E) return;
    int is64 = flags[0], isbf = flags[1];
    int r = ld_idx(ei, is64, e);
    int c = ld_idx(ei, is64, (size_t)E + e);
    float nr = dinv[r] * ldf(ew, isbf, e);
    int pos = atomicAdd(&cursor[c], 1);
    epk[pos] = make_int2(r, __float_as_int(nr));
}

// --- register-blocked GEMM: H[N,FOUT] = X[N,FIN] @ W[FIN,FOUT] (+b, ELU)
template <int FIN, int FOUT, int TM, int TN, bool ADAPT, bool BIAS, bool ELU>
__global__ __launch_bounds__(256) void k_gemm(const void* __restrict__ X,
                                              const void* __restrict__ W,
                                              const void* __restrict__ bias,
                                              const int* __restrict__ flags,
                                              float* __restrict__ H) {
    constexpr int TCOLS = FOUT / TN;
    constexpr int TROWS = 256 / TCOLS;
    constexpr int BR = TROWS * TM;
    __shared__ float wl[FIN * FOUT];
    __shared__ float xt[FIN][BR + 1];
    int t = threadIdx.x;
    int isbf = flags[1];
    int base = blockIdx.x * BR;

    if (!isbf) {
        const float4* W4 = (const float4*)W;
        float4* wl4 = (float4*)wl;
        for (int i = t; i < FIN * FOUT / 4; i += 256) wl4[i] = W4[i];
    } else {
        for (int i = t; i < FIN * FOUT; i += 256)
            wl[i] = __bfloat162float(((const __hip_bfloat16*)W)[i]);
    }
    if (!ADAPT || !isbf) {
        const float4* X4 = (const float4*)X;
        for (int i = t; i < BR * FIN / 4; i += 256) {
            int row = i / (FIN / 4);
            int kq = i % (FIN / 4);
            int node = base + row;
            float4 v = make_float4(0.f, 0.f, 0.f, 0.f);
            if (node < N) v = X4[(size_t)node * (FIN / 4) + kq];
            int k = kq * 4;
            xt[k][row] = v.x; xt[k + 1][row] = v.y;
            xt[k + 2][row] = v.z; xt[k + 3][row] = v.w;
        }
    } else {
        for (int i = t; i < BR * FIN; i += 256) {
            int row = i / FIN, k = i % FIN;
            int node = base + row;
            float v = (node < N)
                ? __bfloat162float(((const __hip_bfloat16*)X)[(size_t)node * FIN + k]) : 0.f;
            xt[k][row] = v;
        }
    }
    __syncthreads();

    int tcol = t % TCOLS, trow = t / TCOLS;
    int r0 = trow * TM, c0 = tcol * TN;
    float acc[TM][TN] = {};
#pragma unroll 4
    for (int k = 0; k < FIN; k++) {
        float a[TM], b[TN];
#pragma unroll
        for (int m = 0; m < TM; m++) a[m] = xt[k][r0 + m];
#pragma unroll
        for (int n = 0; n < TN; n++) b[n] = wl[k * FOUT + c0 + n];
#pragma unroll
        for (int m = 0; m < TM; m++)
#pragma unroll
            for (int n = 0; n < TN; n++) acc[m][n] += a[m] * b[n];
    }
#pragma unroll
    for (int m = 0; m < TM; m++) {
        int node = base + r0 + m;
        if (node >= N) continue;
#pragma unroll
        for (int n = 0; n < TN; n++) {
            float v = acc[m][n];
            if (BIAS) v += ldf(bias, isbf, c0 + n);
            if (ELU) v = (v > 0.0f) ? v : expm1f(v);
            H[(size_t)node * FOUT + c0 + n] = v;
        }
    }
}

// --- aggregation: out[n] = di*Σ_e w'_e*H[src_e] + di^2*H[n] (+b, ELU)
// (w' = dinv[src]*ew stored in CSR; dinv[target]=di applied here once)
template <int F, bool BIAS, bool ELU>
__global__ __launch_bounds__(256) void k_agg(const float4* __restrict__ H4,
                                             const int* __restrict__ offsets,
                                             const int* __restrict__ counts,
                                             const int2* __restrict__ epk,
                                             const float* __restrict__ dinv,
                                             const void* __restrict__ bias,
                                             const int* __restrict__ flags,
                                             float4* __restrict__ out4) {
    constexpr int LPN = F / 4;        // lanes per node
    constexpr int NPB = 256 / LPN;    // nodes per block
    constexpr int STR = F / 4;        // float4 stride per row
    int t = threadIdx.x;
    int lane = t % LPN;
    int g = t / LPN;
    int node = blockIdx.x * NPB + g;
    if (node >= N) return;
    float di = dinv[node];
    float4 h = H4[(size_t)node * STR + lane];
    float4 acc = make_float4(0.f, 0.f, 0.f, 0.f);
    int p = offsets[node];
    int pend = p + counts[node];
    for (; p + 4 <= pend; p += 4) {
        int2 e0 = epk[p], e1 = epk[p + 1], e2 = epk[p + 2], e3 = epk[p + 3];
        float4 h0 = H4[(size_t)e0.x * STR + lane];
        float4 h1 = H4[(size_t)e1.x * STR + lane];
        float4 h2 = H4[(size_t)e2.x * STR + lane];
        float4 h3 = H4[(size_t)e3.x * STR + lane];
        float w0 = __int_as_float(e0.y), w1 = __int_as_float(e1.y);
        float w2 = __int_as_float(e2.y), w3 = __int_as_float(e3.y);
        acc.x += h0.x * w0 + h1.x * w1 + h2.x * w2 + h3.x * w3;
        acc.y += h0.y * w0 + h1.y * w1 + h2.y * w2 + h3.y * w3;
        acc.z += h0.z * w0 + h1.z * w1 + h2.z * w2 + h3.z * w3;
        acc.w += h0.w * w0 + h1.w * w1 + h2.w * w2 + h3.w * w3;
    }
    for (; p < pend; p++) {
        int2 e = epk[p];
        float4 hh = H4[(size_t)e.x * STR + lane];
        float w = __int_as_float(e.y);
        acc.x += hh.x * w; acc.y += hh.y * w; acc.z += hh.z * w; acc.w += hh.w * w;
    }
    float sw = di * di;
    acc.x = acc.x * di + h.x * sw;
    acc.y = acc.y * di + h.y * sw;
    acc.z = acc.z * di + h.z * sw;
    acc.w = acc.w * di + h.w * sw;
    if (BIAS) {
        int fb = lane * 4;
        int isbf = flags[1];
        acc.x += ldf(bias, isbf, fb);
        acc.y += ldf(bias, isbf, fb + 1);
        acc.z += ldf(bias, isbf, fb + 2);
        acc.w += ldf(bias, isbf, fb + 3);
    }
    if (ELU) {
        acc.x = (acc.x > 0.0f) ? acc.x : expm1f(acc.x);
        acc.y = (acc.y > 0.0f) ? acc.y : expm1f(acc.y);
        acc.z = (acc.z > 0.0f) ? acc.z : expm1f(acc.z);
        acc.w = (acc.w > 0.0f) ? acc.w : expm1f(acc.w);
    }
    out4[(size_t)node * STR + lane] = acc;
}

// diagnostic fallback: if ws_size too small, emit sentinel 123.0
__global__ void k_sentinel(float* out, int n) {
    int i = blockIdx.x * blockDim.x + threadIdx.x;
    if (i < n) out[i] = 123.0f;
}

extern "C" void kernel_launch(void* const* d_in, const int* in_sizes, int n_in,
                              void* d_out, int out_size, void* d_ws, size_t ws_size,
                              hipStream_t stream) {
    const void* x  = d_in[0];
    const void* ei = d_in[1];
    const void* ea = d_in[2];
    const void* W1 = d_in[3];
    const void* b1 = d_in[4];
    const void* W2 = d_in[5];
    const void* b2 = d_in[6];
    const void* W3 = d_in[7];
    const void* b3 = d_in[8];
    float* out = (float*)d_out;

    // workspace layout (256B aligned)
    char* ws = (char*)d_ws;
    size_t off = 0;
    auto alloc = [&](size_t bytes) {
        off = (off + 255) & ~(size_t)255;
        size_t r = off;
        off += bytes;
        return r;
    };
    unsigned long long* packed = (unsigned long long*)(ws + alloc((size_t)N * 8));
    float* dinv    = (float*)(ws + alloc((size_t)N * 4));
    int*   counts  = (int*)  (ws + alloc((size_t)N * 4));
    int*   offsets = (int*)  (ws + alloc((size_t)N * 4));
    int*   cursor  = (int*)  (ws + alloc((size_t)N * 4));
    int*   bsum    = (int*)  (ws + alloc(256 * 4));
    int*   flags   = (int*)  (ws + alloc(256));
    int2*  epk     = (int2*) (ws + alloc((size_t)E * 8));
    float* bufA    = (float*)(ws + alloc((size_t)N * 64 * 4));
    float* bufB    = (float*)(ws + alloc((size_t)N * 64 * 4));
    size_t need = off;

    if (ws_size < need) {
        hipLaunchKernelGGL(k_sentinel, dim3((N * 128 + 255) / 256), dim3(256), 0, stream,
                           out, N * 128);
        return;
    }

    const int TB = 256;
    const int gN = (N + TB - 1) / TB;
    const int gE = (E + TB - 1) / TB;

    hipLaunchKernelGGL(k_probe, dim3(1), dim3(256), 0, stream, ei, x, flags);
    hipLaunchKernelGGL(k_init, dim3(gN), dim3(TB), 0, stream, packed);
    hipLaunchKernelGGL(k_deg_count, dim3(gE), dim3(TB), 0, stream, ei, flags, ea, packed);
    hipLaunchKernelGGL(k_dinv, dim3(gN), dim3(TB), 0, stream, packed, counts, dinv);
    hipLaunchKernelGGL(k_scan_partial, dim3(NB), dim3(256), 0, stream, counts, bsum);
    hipLaunchKernelGGL(k_scan_top, dim3(1), dim3(256), 0, stream, bsum);
    hipLaunchKernelGGL(k_scan_apply, dim3(NB), dim3(256), 0, stream, counts, bsum, offsets, cursor);
    hipLaunchKernelGGL(k_fill, dim3(gE), dim3(TB), 0, stream, ei, flags, ea, dinv, cursor, epk);

    // L1: t1 = x@W1 (bufA, F=32); a1 = ELU(agg(t1)+b1) (bufB)
    hipLaunchKernelGGL((k_gemm<128, 32, 2, 4, true, false, false>),
                       dim3((N + 63) / 64), dim3(256), 0, stream, x, W1, nullptr, flags, bufA);
    hipLaunchKernelGGL((k_agg<32, true, true>), dim3((N + 31) / 32), dim3(256), 0, stream,
                       (const float4*)bufA, offsets, counts, epk, dinv, b1, flags, (float4*)bufB);
    // L2: s2 = agg(a1) (bufA, F=32); h2 = ELU(s2@W2+b2) (bufB, F=64)
    hipLaunchKernelGGL((k_agg<32, false, false>), dim3((N + 31) / 32), dim3(256), 0, stream,
                       (const float4*)bufB, offsets, counts, epk, dinv, nullptr, flags, (float4*)bufA);
    hipLaunchKernelGGL((k_gemm<32, 64, 4, 4, false, true, true>),
                       dim3((N + 63) / 64), dim3(256), 0, stream, bufA, W2, b2, flags, bufB);
    // L3: s3 = agg(h2) (bufA, F=64); out = s3@W3+b3 (d_out, F=128)
    hipLaunchKernelGGL((k_agg<64, false, false>), dim3((N + 15) / 16), dim3(256), 0, stream,
                       (const float4*)bufB, offsets, counts, epk, dinv, nullptr, flags, (float4*)bufA);
    hipLaunchKernelGGL((k_gemm<64, 128, 4, 8, false, true, false>),
                       dim3((N + 63) / 64), dim3(256), 0, stream, bufA, W3, b3, flags, out);
}